// Round 5
// baseline (684.304 us; speedup 1.0000x reference)
//
#include <hip/hip_runtime.h>
#include <stdint.h>

// ---------------------------------------------------------------------------
// AstroSymbolicEpisodicLayer  (B=4, TQ=TK=2048, D=1024, R=64, H=512)
// R5: R4 with the BK=64 LDS fragment-read OOB bug fixed (kk=1 address was
// row*64 + 32 + c1; c1 already encodes the full swizzled chunk position).
// ---------------------------------------------------------------------------

#define Bq 4
#define Tq 2048
#define Dd 1024
#define NT 8192      // B*T
#define Hh 512
#define Rr_ 64
#define FQ 1024      // packed rfft spectrum: re(0..512) | im(1..511)

typedef unsigned short ushort_t;
typedef short s16x8 __attribute__((ext_vector_type(8)));
typedef float floatx4 __attribute__((ext_vector_type(4)));

__device__ __forceinline__ float b2f(ushort_t s) {
  unsigned u = (unsigned)s << 16;
  return __builtin_bit_cast(float, u);
}
__device__ __forceinline__ ushort_t f2b(float f) {
  unsigned u = __builtin_bit_cast(unsigned, f);
  unsigned r = (u + 0x7fffu + ((u >> 16) & 1u)) >> 16;
  return (ushort_t)r;
}

__device__ __forceinline__ void load_lds16(const void* g, void* l) {
  __builtin_amdgcn_global_load_lds((__attribute__((address_space(1))) void*)(g),
                                   (__attribute__((address_space(3))) void*)(l),
                                   16, 0, 0);
}

// ---------------------------------------------------------------------------
// GEMM: C[M,N] = A[M,K] @ Bt[N,K]^T, tile 128x128, BK=64, 4 waves.
// Epilogue: flags&2 ? v = acc*rm*cm + bias : v = (acc + bias)*rm*cm;
// relu (flags&1); Epanechnikov if tau; rsMode 1/2: atomic rowsum of v / v^2.
// LDS: row stride 64 elems (128 B); chunk c (8 elems) of row r stored at
// physical chunk (c + (r&7)) & 7 (bijective per row). Staging lane L writes
// phys chunk L&7 of row base+(L>>3) (global_load_lds dest is lane-fixed), so
// it fetches global chunk ((L&7)-(L>>3))&7. Fragment read for row fr,
// k-group g, k-half kk reads phys chunk (g + 4*kk + (fr&7)) & 7; each 8-lane
// octet covers all 8 chunk positions -> conflict-free.
// ---------------------------------------------------------------------------
__global__ __launch_bounds__(256) void gemm_bt(
    const ushort_t* __restrict__ A, const ushort_t* __restrict__ Bt,
    float* __restrict__ C, ushort_t* __restrict__ Cbf,
    const float* __restrict__ bias_col, const float* __restrict__ bias_row,
    const float* __restrict__ rmul, int rmulStride,
    const float* __restrict__ cmul, int cmulStride,
    const float* __restrict__ tau,
    float* __restrict__ rowsum, int rsStride, int rsMode,
    int K, int lda, int ldb, int ldc,
    long long sA, long long sB, long long sC, int flags)
{
  __shared__ __align__(16) ushort_t As[128 * 64];
  __shared__ __align__(16) ushort_t Bs[128 * 64];

  const int bz   = blockIdx.z;
  const ushort_t* Ab = A + (size_t)bz * sA;
  const ushort_t* Bb = Bt + (size_t)bz * sB;
  const int tm   = blockIdx.y * 128;
  const int tn   = blockIdx.x * 128;
  const int tid  = threadIdx.x;
  const int wave = tid >> 6;
  const int lane = tid & 63;
  const int wm   = (wave & 1) << 6;
  const int wn   = (wave >> 1) << 6;
  // staging
  const int srow = lane >> 3;                      // 0..7
  const int sc   = (((lane & 7) - srow) & 7) << 3; // global elem offset
  // fragment reads
  const int fr = lane & 15;
  const int g  = lane >> 4;
  const int c0 = (((g     + (fr & 7)) & 7) << 3);  // kk=0 phys elem offset
  const int c1 = (((g + 4 + (fr & 7)) & 7) << 3);  // kk=1 phys elem offset

  floatx4 acc[4][4] = {};

  const ushort_t* gA = Ab + (size_t)(tm + wave * 32 + srow) * lda + sc;
  const ushort_t* gB = Bb + (size_t)(tn + wave * 32 + srow) * ldb + sc;
  char* lA = (char*)As + wave * 4096;
  char* lB = (char*)Bs + wave * 4096;

  for (int k0 = 0; k0 < K; k0 += 64) {
#pragma unroll
    for (int q = 0; q < 4; q++) {
      load_lds16(gA + (size_t)(q * 8) * lda + k0, lA + q * 1024);
      load_lds16(gB + (size_t)(q * 8) * ldb + k0, lB + q * 1024);
    }
    __syncthreads();
    {
      s16x8 af[4], bfv[4];
#pragma unroll
      for (int i = 0; i < 4; i++)
        af[i] = *(const s16x8*)&As[(wm + i * 16 + fr) * 64 + c0];
#pragma unroll
      for (int j = 0; j < 4; j++)
        bfv[j] = *(const s16x8*)&Bs[(wn + j * 16 + fr) * 64 + c0];
#pragma unroll
      for (int i = 0; i < 4; i++)
#pragma unroll
        for (int j = 0; j < 4; j++)
          acc[i][j] = __builtin_amdgcn_mfma_f32_16x16x32_bf16(af[i], bfv[j], acc[i][j], 0, 0, 0);
    }
    {
      s16x8 af[4], bfv[4];
#pragma unroll
      for (int i = 0; i < 4; i++)
        af[i] = *(const s16x8*)&As[(wm + i * 16 + fr) * 64 + c1];
#pragma unroll
      for (int j = 0; j < 4; j++)
        bfv[j] = *(const s16x8*)&Bs[(wn + j * 16 + fr) * 64 + c1];
#pragma unroll
      for (int i = 0; i < 4; i++)
#pragma unroll
        for (int j = 0; j < 4; j++)
          acc[i][j] = __builtin_amdgcn_mfma_f32_16x16x32_bf16(af[i], bfv[j], acc[i][j], 0, 0, 0);
    }
    __syncthreads();
  }

  // ---- epilogue ----
  const float tv = tau ? tau[bz] : 0.f;
  float*   Cp  = C   ? C   + (size_t)bz * sC : nullptr;
  ushort_t* Cb = Cbf ? Cbf + (size_t)bz * sC : nullptr;
  float bcv[4], cmv[4];
#pragma unroll
  for (int j = 0; j < 4; j++) {
    const int col = tn + wn + j * 16 + (lane & 15);
    bcv[j] = bias_col ? bias_col[col] : 0.f;
    cmv[j] = cmul ? cmul[(size_t)bz * cmulStride + col] : 1.f;
  }
#pragma unroll
  for (int i = 0; i < 4; i++) {
#pragma unroll
    for (int r = 0; r < 4; r++) {
      const int row = tm + wm + i * 16 + (lane >> 4) * 4 + r;
      const float rm = rmul ? rmul[(size_t)bz * rmulStride + row] : 1.f;
      const float br = bias_row ? bias_row[row] : 0.f;
      float rsum = 0.f;
#pragma unroll
      for (int j = 0; j < 4; j++) {
        const int col = tn + wn + j * 16 + (lane & 15);
        float v;
        if (flags & 2) v = acc[i][j][r] * rm * cmv[j] + bcv[j] + br;
        else           v = (acc[i][j][r] + bcv[j] + br) * rm * cmv[j];
        if (flags & 1) v = fmaxf(v, 0.f);
        if (tau) { float d = 1.0f - v; v = fmaxf(1.0f - tv * 0.25f * d * d, 0.f); }
        rsum += (rsMode == 2) ? v * v : v;
        if (Cp) Cp[(size_t)row * ldc + col] = v;
        if (Cb) Cb[(size_t)row * ldc + col] = f2b(v);
      }
      if (rsMode == 1 || rsMode == 2) {
        rsum += __shfl_xor(rsum, 1);
        rsum += __shfl_xor(rsum, 2);
        rsum += __shfl_xor(rsum, 4);
        rsum += __shfl_xor(rsum, 8);
        if ((lane & 15) == 0)
          atomicAdd(&rowsum[(size_t)bz * rsStride + row], rsum);
      }
    }
  }
}

// ---------------------------------------------------------------------------
// small kernels
// ---------------------------------------------------------------------------
struct CastM { const float* in[4]; ushort_t* out[4]; int n4[4]; };
__global__ __launch_bounds__(256) void castM_kernel(CastM p) {
  int z = blockIdx.z;
  int i = blockIdx.x * 256 + threadIdx.x;
  if (i >= p.n4[z]) return;
  float4 v = ((const float4*)p.in[z])[i];
  ushort4 o;
  o.x = f2b(v.x); o.y = f2b(v.y); o.z = f2b(v.z); o.w = f2b(v.w);
  ((ushort4*)p.out[z])[i] = o;
}

struct TC3 { const float* in[3]; ushort_t* out[3]; };
// 3x fused 1024x1024 transpose+cast. grid(32,32,3), block(32,8)
__global__ __launch_bounds__(256) void tcast3(TC3 p) {
  __shared__ float t[32][33];
  int z = blockIdx.z;
  const float* in = p.in[z];
  ushort_t* out = p.out[z];
  int r0 = blockIdx.x * 32, c0 = blockIdx.y * 32;
  int x = threadIdx.x, y = threadIdx.y;
  for (int dy = 0; dy < 32; dy += 8)
    t[y + dy][x] = in[(size_t)(r0 + y + dy) * 1024 + c0 + x];
  __syncthreads();
  for (int dy = 0; dy < 32; dy += 8)
    out[(size_t)(c0 + y + dy) * 1024 + r0 + x] = f2b(t[x][y + dy]);
}

// out[c][r] = (c<Cc ? in[r][c] : 0), out has Cp rows. grid(RrN/32, Cp/32), block(32,8)
__global__ __launch_bounds__(256) void tcast(const float* __restrict__ in,
                                             ushort_t* __restrict__ out,
                                             int RrN, int Cc, int Cp) {
  __shared__ float t[32][33];
  int r0 = blockIdx.x * 32, c0 = blockIdx.y * 32;
  int x = threadIdx.x, y = threadIdx.y;
  for (int dy = 0; dy < 32; dy += 8) {
    int r = r0 + y + dy, c = c0 + x;
    t[y + dy][x] = (c < Cc) ? in[(size_t)r * Cc + c] : 0.f;
  }
  __syncthreads();
  for (int dy = 0; dy < 32; dy += 8) {
    int c = c0 + y + dy, r = r0 + x;
    if (c < Cp) out[(size_t)c * RrN + r] = f2b(t[x][y + dy]);
  }
}

// normalize role_matrix rows (64 x 1024) -> bf16 row-major rmn (64 x 1024)
__global__ __launch_bounds__(256) void rolenorm(const float* __restrict__ rm,
                                                ushort_t* __restrict__ rmn) {
  int r = blockIdx.x, tid = threadIdx.x;
  float4 v = ((const float4*)(rm + (size_t)r * 1024))[tid];
  float s = v.x * v.x + v.y * v.y + v.z * v.z + v.w * v.w;
#pragma unroll
  for (int m = 1; m < 64; m <<= 1) s += __shfl_xor(s, m);
  __shared__ float red[6];
  if ((tid & 63) == 0) red[tid >> 6] = s;
  __syncthreads();
  if (tid == 0) red[4] = 1.f / fmaxf(sqrtf(red[0] + red[1] + red[2] + red[3]), 1e-12f);
  __syncthreads();
  float inv = red[4];
  ushort4 o;
  o.x = f2b(v.x * inv); o.y = f2b(v.y * inv); o.z = f2b(v.z * inv); o.w = f2b(v.w * inv);
  ((ushort4*)(rmn + (size_t)r * 1024))[tid] = o;
}

// RFnT[j,r] = sum_k FTab[j,k] * rmn[r,k]; j<1024, r<64, out ld 128
__global__ __launch_bounds__(256) void rfn_kernel(const ushort_t* __restrict__ rmn,
                                                  const ushort_t* __restrict__ ftab,
                                                  ushort_t* __restrict__ RFnT) {
  int f = blockIdx.x;
  int t = threadIdx.x;
  int r = t >> 2, part = t & 3;
  const ushort_t* fr = ftab + (size_t)f * 1024 + part * 256;
  const ushort_t* rr = rmn + (size_t)r * 1024 + part * 256;
  float s = 0.f;
#pragma unroll 4
  for (int i = 0; i < 32; i++) {
    s16x8 a = *(const s16x8*)(fr + i * 8);
    s16x8 b = *(const s16x8*)(rr + i * 8);
#pragma unroll
    for (int j = 0; j < 8; j++) s += b2f((ushort_t)a[j]) * b2f((ushort_t)b[j]);
  }
  s += __shfl_xor(s, 1);
  s += __shfl_xor(s, 2);
  if (part == 0) RFnT[(size_t)f * 128 + r] = f2b(s);
}

// bvo[d] = dot(WoT[d,:], bv)  -- grid 256, block 256 (4 waves, 1 d each)
__global__ __launch_bounds__(256) void bvo_kernel(const ushort_t* __restrict__ WoT,
                                                  const float* __restrict__ bv,
                                                  float* __restrict__ bvo) {
  int d = blockIdx.x * 4 + (threadIdx.x >> 6);
  int lane = threadIdx.x & 63;
  const ushort_t* row = WoT + (size_t)d * 1024;
  float s = 0.f;
#pragma unroll
  for (int i = 0; i < 16; i++) s += b2f(row[lane + 64 * i]) * bv[lane + 64 * i];
#pragma unroll
  for (int m = 1; m < 64; m <<= 1) s += __shfl_xor(s, m);
  if (lane == 0) bvo[d] = s;
}

// invQ = 1/max(||row||,eps); ssum[b] += ||row||  (NT threads)
__global__ __launch_bounds__(256) void invnorm_surprise(const float* __restrict__ ssq,
                                                        float* __restrict__ invn,
                                                        float* __restrict__ ssum) {
  int row = blockIdx.x * 256 + threadIdx.x;
  float nrm = sqrtf(ssq[row]);
  invn[row] = 1.f / fmaxf(nrm, 1e-12f);
  float t = nrm;
#pragma unroll
  for (int m = 1; m < 64; m <<= 1) t += __shfl_xor(t, m);
  if ((threadIdx.x & 63) == 0) atomicAdd(&ssum[row >> 11], t);
}

__global__ __launch_bounds__(256) void invnorm(const float* __restrict__ ssq,
                                               float* __restrict__ invn) {
  int row = blockIdx.x * 256 + threadIdx.x;
  invn[row] = 1.f / fmaxf(sqrtf(ssq[row]), 1e-12f);
}

__global__ __launch_bounds__(256) void invrowsum(const float* __restrict__ rs,
                                                 float* __restrict__ inv) {
  int row = blockIdx.x * 256 + threadIdx.x;
  inv[row] = 1.f / fmaxf(rs[row], 1e-9f);
}

__global__ void finalize_astro(const float* __restrict__ ssum, const float* __restrict__ astro,
                               const float* __restrict__ ascale, float* __restrict__ tau,
                               float* __restrict__ outTail) {
  int b = threadIdx.x;
  if (b < Bq) {
    float mean = ssum[b] * (1.f / (32.f * 2048.f));  // norm/sqrt(D), averaged over TQ
    float ns = 0.95f * astro[b] + 0.05f * mean;
    tau[b] = fmaxf(1.f + ascale[0] * ns, 0.001f);
    outTail[b] = ns;
  }
}

// softmax over 64 logits per row (logits stride 128), out bf16 (rows x 64)
__global__ __launch_bounds__(256) void softmax64(const float* __restrict__ logits,
                                                 ushort_t* __restrict__ out) {
  int row = blockIdx.x * 4 + (threadIdx.x >> 6);
  int lane = threadIdx.x & 63;
  float x = logits[(size_t)row * 128 + lane];
  float m = x;
#pragma unroll
  for (int s = 1; s < 64; s <<= 1) m = fmaxf(m, __shfl_xor(m, s));
  float e = expf(x - m);
  float sum = e;
#pragma unroll
  for (int s = 1; s < 64; s <<= 1) sum += __shfl_xor(sum, s);
  out[(size_t)row * 64 + lane] = f2b(e / sum);
}

// packed forward DFT table (1024 rows j x 1024 cols k)
__global__ __launch_bounds__(256) void gen_ftab(ushort_t* __restrict__ ftab) {
  const float TW = 6.283185307179586f / 1024.f;
  int idx = blockIdx.x * 256 + threadIdx.x;
  int j = idx >> 10, k = idx & 1023;
  int f = j <= 512 ? j : j - 512;
  float th = (float)((f * k) & 1023) * TW;
  float sv, cv; sincosf(th, &sv, &cv);
  ftab[idx] = f2b(j <= 512 ? cv : -sv);
}
// packed inverse table (1024 rows n x 1024 cols j)
__global__ __launch_bounds__(256) void gen_itab(ushort_t* __restrict__ itab) {
  const float TW = 6.283185307179586f / 1024.f;
  int idx = blockIdx.x * 256 + threadIdx.x;
  int n = idx >> 10, j = idx & 1023;
  float v;
  if (j <= 512) {
    float w = (j == 0 || j == 512) ? (1.f / 1024.f) : (2.f / 1024.f);
    float th = (float)((j * n) & 1023) * TW;
    float sv, cv; sincosf(th, &sv, &cv);
    v = w * cv;
  } else {
    int f = j - 512;
    float th = (float)((f * n) & 1023) * TW;
    float sv, cv; sincosf(th, &sv, &cv);
    v = -(2.f / 1024.f) * sv;
  }
  itab[idx] = f2b(v);
}

// packed pointwise complex product
__global__ __launch_bounds__(256) void fftmul(const ushort_t* __restrict__ KF,
                                              const ushort_t* __restrict__ RF,
                                              ushort_t* __restrict__ P) {
  int idx = blockIdx.x * 256 + threadIdx.x;   // [0, NT*512)
  int t = idx >> 9;
  int j = idx & 511;
  size_t base = (size_t)t * FQ;
  if (j == 0) {
    P[base]       = f2b(b2f(KF[base]) * b2f(RF[base]));
    P[base + 512] = f2b(b2f(KF[base + 512]) * b2f(RF[base + 512]));
  } else {
    float a = b2f(KF[base + j]), b = b2f(KF[base + 512 + j]);
    float c = b2f(RF[base + j]), d = b2f(RF[base + 512 + j]);
    P[base + j]       = f2b(a * c - b * d);
    P[base + 512 + j] = f2b(a * d + b * c);
  }
}

// ---------------------------------------------------------------------------
// workspace layout (bytes, 256-aligned)
// ---------------------------------------------------------------------------
static constexpr size_t OFF_RS    = 0;                      // 32 KB
static constexpr size_t OFF_SSQQ  = 32768;
static constexpr size_t OFF_SSQK  = 65536;
static constexpr size_t OFF_INVQ  = 98304;
static constexpr size_t OFF_INVK  = 131072;
static constexpr size_t OFF_INVRS = 163840;
static constexpr size_t OFF_SSUM  = 196608;                 // 16 B
static constexpr size_t OFF_TAU   = 196864;                 // 16 B
static constexpr size_t OFF_BVO   = 197120;                 // 4 KB
static constexpr size_t OFF_WQT   = 201216;
static constexpr size_t OFF_WKT   = OFF_WQT  + 2097152;
static constexpr size_t OFF_WOT   = OFF_WKT  + 2097152;
static constexpr size_t OFF_WVBF  = OFF_WOT  + 2097152;
static constexpr size_t OFF_WVOT  = OFF_WVBF + 2097152;
static constexpr size_t OFF_WR1T  = OFF_WVOT + 2097152;
static constexpr size_t OFF_WR2T  = OFF_WR1T + 1048576;
static constexpr size_t OFF_RMN   = OFF_WR2T + 131072;
static constexpr size_t OFF_FTAB  = OFF_RMN  + 131072;
static constexpr size_t OFF_ITAB  = OFF_FTAB + 2097152;
static constexpr size_t OFF_RFNT  = OFF_ITAB + 2097152;     // 1024x128 bf16
static constexpr size_t OFF_B1    = OFF_RFNT + 262144;      // qbf -> KF   (16MB)
static constexpr size_t OFF_B2    = OFF_B1   + 16777216;    // kinb -> RF  (16MB)
static constexpr size_t OFF_B3    = OFF_B2   + 16777216;    // vinb -> Pb  (16MB)
static constexpr size_t OFF_B4    = OFF_B3   + 16777216;    // qraw        (16MB)
static constexpr size_t OFF_B5    = OFF_B4   + 16777216;    // kbraw       (16MB)
static constexpr size_t OFF_B6    = OFF_B5   + 16777216;    // kp          (16MB)
static constexpr size_t OFF_B7    = OFF_B6   + 16777216;    // VoT         (16MB)
static constexpr size_t OFF_HID   = OFF_B7   + 16777216;    // 8MB
static constexpr size_t OFF_LOGI  = OFF_HID  + 8388608;     // 4MB
static constexpr size_t OFF_RW    = OFF_LOGI + 4194304;     // 1MB
static constexpr size_t OFF_SB    = OFF_RW   + 1048576;     // 32MB scores
static constexpr size_t WS_NEEDED = OFF_SB   + 33554432;    // ~178 MB

static inline void launch_gemm(hipStream_t s, const ushort_t* A, const ushort_t* Bt,
                               float* Cf, ushort_t* Cb,
                               const float* bias_col, const float* bias_row,
                               const float* rmul, int rmulStride,
                               const float* cmul, int cmulStride,
                               const float* tau, float* rowsum, int rsStride, int rsMode,
                               int M, int N, int K, int lda, int ldb, int ldc,
                               long long sA, long long sB, long long sC, int Z, int flags) {
  dim3 g(N / 128, M / 128, Z), b(256);
  gemm_bt<<<g, b, 0, s>>>(A, Bt, Cf, Cb, bias_col, bias_row, rmul, rmulStride,
                          cmul, cmulStride, tau, rowsum, rsStride, rsMode,
                          K, lda, ldb, ldc, sA, sB, sC, flags);
}

extern "C" void kernel_launch(void* const* d_in, const int* in_sizes, int n_in,
                              void* d_out, int out_size, void* d_ws, size_t ws_size,
                              hipStream_t stream) {
  (void)in_sizes; (void)n_in; (void)out_size;
  if (ws_size < WS_NEEDED) return;

  const float* q_in  = (const float*)d_in[0];
  const float* k_in  = (const float*)d_in[1];
  const float* v_in  = (const float*)d_in[2];
  const float* astro = (const float*)d_in[3];
  const float* Wq    = (const float*)d_in[4];
  const float* bq    = (const float*)d_in[5];
  const float* Wk    = (const float*)d_in[6];
  const float* bk    = (const float*)d_in[7];
  const float* Wv    = (const float*)d_in[8];
  const float* bv    = (const float*)d_in[9];
  const float* Wo    = (const float*)d_in[10];
  const float* bo    = (const float*)d_in[11];
  const float* roleM = (const float*)d_in[12];
  const float* Wr1   = (const float*)d_in[13];
  const float* br1   = (const float*)d_in[14];
  const float* Wr2   = (const float*)d_in[15];
  const float* ascl  = (const float*)d_in[16];

  char* ws = (char*)d_ws;
  float*    rowsumS = (float*)(ws + OFF_RS);
  float*    ssqQ    = (float*)(ws + OFF_SSQQ);
  float*    ssqK    = (float*)(ws + OFF_SSQK);
  float*    invQ    = (float*)(ws + OFF_INVQ);
  float*    invK    = (float*)(ws + OFF_INVK);
  float*    invRS   = (float*)(ws + OFF_INVRS);
  float*    ssum    = (float*)(ws + OFF_SSUM);
  float*    tau     = (float*)(ws + OFF_TAU);
  float*    bvo     = (float*)(ws + OFF_BVO);
  ushort_t* WqT  = (ushort_t*)(ws + OFF_WQT);
  ushort_t* WkT  = (ushort_t*)(ws + OFF_WKT);
  ushort_t* WoT  = (ushort_t*)(ws + OFF_WOT);
  ushort_t* Wvbf = (ushort_t*)(ws + OFF_WVBF);
  ushort_t* WvoT = (ushort_t*)(ws + OFF_WVOT);
  ushort_t* Wr1T = (ushort_t*)(ws + OFF_WR1T);
  ushort_t* Wr2T = (ushort_t*)(ws + OFF_WR2T);
  ushort_t* rmn  = (ushort_t*)(ws + OFF_RMN);
  ushort_t* FTab = (ushort_t*)(ws + OFF_FTAB);
  ushort_t* ITab = (ushort_t*)(ws + OFF_ITAB);
  ushort_t* RFnT = (ushort_t*)(ws + OFF_RFNT);
  ushort_t* qbf  = (ushort_t*)(ws + OFF_B1);
  ushort_t* KF   = (ushort_t*)(ws + OFF_B1);
  ushort_t* kinb = (ushort_t*)(ws + OFF_B2);
  ushort_t* RF   = (ushort_t*)(ws + OFF_B2);
  ushort_t* vinb = (ushort_t*)(ws + OFF_B3);
  ushort_t* Pb   = (ushort_t*)(ws + OFF_B3);
  ushort_t* qraw = (ushort_t*)(ws + OFF_B4);
  ushort_t* kbraw= (ushort_t*)(ws + OFF_B5);
  ushort_t* kp   = (ushort_t*)(ws + OFF_B6);
  ushort_t* VoT  = (ushort_t*)(ws + OFF_B7);
  ushort_t* hid  = (ushort_t*)(ws + OFF_HID);
  float*    logi = (float*)(ws + OFF_LOGI);
  ushort_t* rw   = (ushort_t*)(ws + OFF_RW);
  ushort_t* Sb   = (ushort_t*)(ws + OFF_SB);
  float*    out  = (float*)d_out;

  // 0. zero accumulators
  hipMemsetAsync(ws, 0, OFF_BVO, stream);

  // 1. weight prep + tables
  TC3 tc3;
  tc3.in[0] = Wq; tc3.in[1] = Wk; tc3.in[2] = Wo;
  tc3.out[0] = WqT; tc3.out[1] = WkT; tc3.out[2] = WoT;
  tcast3<<<dim3(32, 32, 3), dim3(32, 8), 0, stream>>>(tc3);
  tcast<<<dim3(32, 16), dim3(32, 8), 0, stream>>>(Wr1, Wr1T, 1024, 512, 512);
  tcast<<<dim3(16, 4),  dim3(32, 8), 0, stream>>>(Wr2, Wr2T, 512, 64, 128);
  rolenorm<<<64, 256, 0, stream>>>(roleM, rmn);
  gen_ftab<<<(FQ * 1024) / 256, 256, 0, stream>>>(FTab);
  gen_itab<<<(1024 * FQ) / 256, 256, 0, stream>>>(ITab);
  rfn_kernel<<<FQ, 256, 0, stream>>>(rmn, FTab, RFnT);

  // 2. casts: q,k,v inputs + Wv (plain)
  CastM cm;
  cm.in[0] = q_in; cm.out[0] = qbf;  cm.n4[0] = NT * Dd / 4;
  cm.in[1] = k_in; cm.out[1] = kinb; cm.n4[1] = NT * Dd / 4;
  cm.in[2] = v_in; cm.out[2] = vinb; cm.n4[2] = NT * Dd / 4;
  cm.in[3] = Wv;   cm.out[3] = Wvbf; cm.n4[3] = Dd * Dd / 4;
  castM_kernel<<<dim3(8192, 1, 4), 256, 0, stream>>>(cm);

  // 3. folded weights: WvoT = (Wv@Wo)^T; bvo = Wo^T @ bv
  bvo_kernel<<<256, 256, 0, stream>>>(WoT, bv, bvo);
  launch_gemm(stream, WoT, Wvbf, nullptr, WvoT, nullptr, nullptr,
              nullptr, 0, nullptr, 0, nullptr, nullptr, 0, 0,
              Dd, Dd, Dd, Dd, Dd, Dd, 0, 0, 0, 1, 0);

  // 4. Q path: proj(+sumsq) -> invnorm+surprise -> tau
  launch_gemm(stream, qbf, WqT, nullptr, qraw, bq, nullptr,
              nullptr, 0, nullptr, 0, nullptr, ssqQ, 0, 2,
              NT, Dd, Dd, Dd, Dd, Dd, 0, 0, 0, 1, 0);
  invnorm_surprise<<<NT / 256, 256, 0, stream>>>(ssqQ, invQ, ssum);
  finalize_astro<<<1, 64, 0, stream>>>(ssum, astro, ascl, tau, out + (size_t)NT * Dd);

  // 5. K path: proj
  launch_gemm(stream, kinb, WkT, nullptr, kp, bk, nullptr,
              nullptr, 0, nullptr, 0, nullptr, nullptr, 0, 0,
              NT, Dd, Dd, Dd, Dd, Dd, 0, 0, 0, 1, 0);

  // 6. VoT = WvoT @ v_in^T + bvo (row bias): (1024 x NT)
  launch_gemm(stream, WvoT, vinb, nullptr, VoT, nullptr, bvo,
              nullptr, 0, nullptr, 0, nullptr, nullptr, 0, 0,
              Dd, NT, Dd, Dd, Dd, NT, 0, 0, 0, 1, 0);

  // 7. role path: MLP -> softmax
  launch_gemm(stream, kp, Wr1T, nullptr, hid, br1, nullptr,
              nullptr, 0, nullptr, 0, nullptr, nullptr, 0, 0,
              NT, Hh, Dd, Dd, Dd, Hh, 0, 0, 0, 1, 1 /*relu*/);
  launch_gemm(stream, hid, Wr2T, logi, nullptr, nullptr, nullptr,
              nullptr, 0, nullptr, 0, nullptr, nullptr, 0, 0,
              NT, 128, Hh, Hh, Hh, 128, 0, 0, 0, 1, 0);
  softmax64<<<NT / 4, 256, 0, stream>>>(logi, rw);

  // 8. binding: KF = kp@FTab^T ; RF = rw@RFnT^T ; pointwise ; inverse(+sumsq)
  launch_gemm(stream, kp, FTab, nullptr, KF, nullptr, nullptr,
              nullptr, 0, nullptr, 0, nullptr, nullptr, 0, 0,
              NT, FQ, Dd, Dd, Dd, FQ, 0, 0, 0, 1, 0);
  launch_gemm(stream, rw, RFnT, nullptr, RF, nullptr, nullptr,
              nullptr, 0, nullptr, 0, nullptr, nullptr, 0, 0,
              NT, FQ, Rr_, Rr_, 128, FQ, 0, 0, 0, 1, 0);
  fftmul<<<(NT * 512) / 256, 256, 0, stream>>>(KF, RF, Pb);
  launch_gemm(stream, Pb, ITab, nullptr, kbraw, nullptr, nullptr,
              nullptr, 0, nullptr, 0, nullptr, ssqK, 0, 2,
              NT, Dd, FQ, FQ, FQ, Dd, 0, 0, 0, 1, 0);
  invnorm<<<NT / 256, 256, 0, stream>>>(ssqK, invK);

  // 9. attention: scores (norm-folded Epanechnikov + rowsum) -> fused ctx+out
  launch_gemm(stream, qraw, kbraw, nullptr, Sb, nullptr, nullptr,
              invQ, Tq, invK, Tq, tau, rowsumS, Tq, 1,
              Tq, Tq, Dd, Dd, Dd, Tq,
              (long long)Tq * Dd, (long long)Tq * Dd, (long long)Tq * Tq, Bq, 0);
  invrowsum<<<NT / 256, 256, 0, stream>>>(rowsumS, invRS);
  launch_gemm(stream, Sb, VoT, out, nullptr, bo, nullptr,
              invRS, Tq, nullptr, 0, nullptr, nullptr, 0, 0,
              Tq, Dd, Tq, Tq, NT, Dd,
              (long long)Tq * Tq, (long long)Tq, (long long)Tq * Dd, Bq, 2 /*scale-then-bias*/);
}